// Round 4
// baseline (146005.542 us; speedup 1.0000x reference)
//
#include <hip/hip_runtime.h>
#include <hip/hip_bf16.h>

// ---------------------------------------------------------------------------
// FULL FLOAT64 pipeline. Rationale: the model re-binarizes xp>0.5 every
// iteration; the np reference is (by round-3 evidence) float64, and fp32
// summation noise (~1e-5 on the sigmoid pre-act, which has ~6.5e5/unit
// density near 0) flips a few pixels' binary features -> localized ~0.05
// errors (observed 4.69e-2). f64 tracks the f64 ref to ~1e-13 -> no flips.
//
// B=4, H=W=256; batches independent (toroidal wrap is per-image); strips of
// R rows with halo recompute, R chosen from ws_size.
//   h0 strip-free (per image):  [65536, 8] f64   (5 feats padded to 8)
//   h1 strip: [(R+4) rows][256][256] f64 ; h2: [(R+2)][256][256] ; h3 = h1
//   packed weights f64: Wp[k*256+oc], k = tap*CIN+cin (tap-major)
//   xp64: [NPIX] f64 state buffer; d_out: [NPIX] f32 (written every iter)
// ---------------------------------------------------------------------------

#define NPIX (4 * 256 * 256)

// ---------------------- x (f32) -> xp64 (f64) init -------------------------
__global__ __launch_bounds__(256) void xinit_kernel(
    const float* __restrict__ x, double* __restrict__ xp64)
{
    int p = blockIdx.x * 256 + threadIdx.x;
    xp64[p] = (double)x[p];
}

// ------------------------- stencil feature kernel (per image) --------------
__global__ __launch_bounds__(256) void stencil_kernel(
    const float* __restrict__ x, const double* __restrict__ xp,
    double* __restrict__ h0, int pbase)
{
    int pl = blockIdx.x * 256 + threadIdx.x;        // [0, 65536)
    int y = pl >> 8, xx = pl & 255;
    double q[8];
    int s = 0, idx = 0;
    #pragma unroll
    for (int i = -1; i <= 1; ++i)
        #pragma unroll
        for (int j = -1; j <= 1; ++j) {
            if (i == 0 && j == 0) continue;
            int ys = (y - i) & 255, xs = (xx - j) & 255;
            double v = xp[pbase + ((ys << 8) | xs)];
            q[idx++] = v;
            s += (v > 0.5) ? 1 : 0;
        }
    double c = xp[pbase + pl];
    bool alive = c > 0.5;
    bool binnext = (s == 3) || (alive && s == 2);
    double c0 = 1.0, c1 = 0.0, c2 = 0.0, c3 = 0.0;  // count DP, ref order
    #pragma unroll
    for (int k = 0; k < 8; ++k) {
        double qq = q[k], r = 1.0 - qq;
        c3 = c3 * r + c2 * qq;
        c2 = c2 * r + c1 * qq;
        c1 = c1 * r + c0 * qq;
        c0 = c0 * r;
    }
    double xpred = c3 + c2 * c;
    double* o = h0 + (size_t)pl * 8;
    o[0] = (double)x[pbase + pl];
    o[1] = c;
    o[2] = alive ? 1.0 : 0.0;
    o[3] = xpred;
    o[4] = binnext ? 1.0 : 0.0;
    o[5] = 0.0; o[6] = 0.0; o[7] = 0.0;
}

// ------------------- f64 direct-conv GEMM (Cout=256) -----------------------
// Block tile: 64 px x 128 oc, 256 threads, 4x8 per thread (f64).
//   WRAP : src row = (out_base_row + yl + dy) & 255    (h0 per-image)
//   !WRAP: src row =  yl + dy + delta                  (strip buffer)
template<int CIN, int KH, int KW, int TK, bool WRAP>
__global__ __launch_bounds__(256, 2) void conv_gemm(
    const double* __restrict__ A,    // [rows, 256, CIN]
    const double* __restrict__ Wp,   // [KH*KW*CIN, 256]
    const float* __restrict__ bias,  // [256] f32
    double* __restrict__ O,          // [Rout, 256, 256]
    int out_base_row, int delta)
{
    constexpr int PH = KH / 2, PW = KW / 2;
    constexpr int CHUNKS = CIN / TK;
    __shared__ double Asmem[TK][66];   // [k][px], pad +2 (16B-aligned rows)
    __shared__ double Wsmem[TK][128];  // [k][oc]

    const int tid = threadIdx.x;
    const int pm0 = blockIdx.x * 64;       // pixel base (local strip px)
    const int on0 = blockIdx.y * 128;      // oc base
    const int tn = tid & 15, tm = tid >> 4;

    // A staging: LPP lanes per pixel, double2 each
    constexpr int LPP = TK / 2;
    constexpr int PPR = 256 / LPP;
    constexpr int ROUNDS = 64 / PPR;
    const int part = tid % LPP;
    const int pixA = tid / LPP;
    // W staging: 64 lanes per 128-double row (double2 each), 4 rows/pass
    const int wrow = tid >> 6;
    const int wcol = (tid & 63) << 1;

    double acc[4][8] = {};

    for (int tap = 0; tap < KH * KW; ++tap) {
        const int dy = tap / KW - PH, dx = tap % KW - PW;
        for (int cc = 0; cc < CHUNKS; ++cc) {
            const int c0 = cc * TK;
            const int kglob = tap * CIN + c0;
            #pragma unroll
            for (int r = 0; r < TK / 4; ++r) {
                int row = r * 4 + wrow;
                *(double2*)&Wsmem[row][wcol] =
                    *(const double2*)&Wp[(size_t)(kglob + row) * 256 + on0 + wcol];
            }
            #pragma unroll
            for (int r = 0; r < ROUNDS; ++r) {
                int pix = r * PPR + pixA;
                int pl = pm0 + pix;
                int yl = pl >> 8, col = pl & 255;
                int xs = (col + dx) & 255;
                int srcpx;
                if (WRAP) srcpx = (((out_base_row + yl + dy) & 255) << 8) | xs;
                else      srcpx = ((yl + dy + delta) << 8) | xs;
                const double2 v = *(const double2*)(
                    A + (size_t)srcpx * CIN + c0 + part * 2);
                Asmem[part * 2 + 0][pix] = v.x;
                Asmem[part * 2 + 1][pix] = v.y;
            }
            __syncthreads();
            #pragma unroll
            for (int k = 0; k < TK; ++k) {
                double av[4], bv[8];
                #pragma unroll
                for (int i = 0; i < 4; ++i) av[i] = Asmem[k][tm * 4 + i];
                #pragma unroll
                for (int j = 0; j < 8; ++j) bv[j] = Wsmem[k][tn * 8 + j];
                #pragma unroll
                for (int i = 0; i < 4; ++i)
                    #pragma unroll
                    for (int j = 0; j < 8; ++j)
                        acc[i][j] = fma(av[i], bv[j], acc[i][j]);
            }
            __syncthreads();
        }
    }

    double bb[8];
    #pragma unroll
    for (int j = 0; j < 8; ++j) bb[j] = (double)bias[on0 + tn * 8 + j];
    #pragma unroll
    for (int i = 0; i < 4; ++i) {
        int pl = pm0 + tm * 4 + i;
        double* dst = O + (size_t)pl * 256 + on0 + tn * 8;
        #pragma unroll
        for (int j = 0; j < 8; j += 2) {
            double2 o;
            o.x = fmax(acc[i][j + 0] + bb[j + 0], 0.0);
            o.y = fmax(acc[i][j + 1] + bb[j + 1], 0.0);
            *(double2*)(dst + j) = o;
        }
    }
}

// --------------- conv4: 256->1, 3x3, + sigmoid, wave-per-pixel -------------
__global__ __launch_bounds__(256) void conv4_sig(
    const double* __restrict__ H3,   // strip [R+2, 256, 256]
    const float* __restrict__ w4, const float* __restrict__ b4,
    float* __restrict__ out,         // global f32 (d_out)
    double* __restrict__ xp64,       // global f64 state
    int pbase, int out_base_row, int delta)
{
    __shared__ double w4s[2304];     // w4[cin][kh][kw] (f64)
    int tid = threadIdx.x;
    for (int i = tid; i < 2304; i += 256) w4s[i] = (double)w4[i];
    __syncthreads();
    int lane = tid & 63, wv = tid >> 6;
    int p0 = blockIdx.x * 64 + wv * 16;
    for (int pi = 0; pi < 16; ++pi) {
        int pl = p0 + pi;
        int yl = pl >> 8, col = pl & 255;
        double acc = 0.0;
        #pragma unroll
        for (int tap = 0; tap < 9; ++tap) {
            int row = yl + tap / 3 - 1 + delta;
            int xs = (col + tap % 3 - 1) & 255;
            const double* src = H3 + (size_t)((row << 8) | xs) * 256;
            #pragma unroll
            for (int j = 0; j < 4; ++j) {
                int c = lane + 64 * j;
                acc = fma(src[c], w4s[c * 9 + tap], acc);
            }
        }
        #pragma unroll
        for (int off = 32; off; off >>= 1) acc += __shfl_xor(acc, off, 64);
        if (lane == 0) {
            double v = acc + (double)b4[0];
            double s = 1.0 / (1.0 + exp(-v));
            int p = pbase + (((out_base_row + yl) << 8) | col);
            out[p] = (float)s;
            xp64[p] = s;
        }
    }
}

// ----------------------------- weight repacks (f32 -> f64) -----------------
__global__ void repack_w1(const float* __restrict__ w1, double* __restrict__ W1p) {
    int t = blockIdx.x * 256 + threadIdx.x;           // [(tap*8+cin)*256+oc]
    if (t >= 25 * 8 * 256) return;
    int oc = t & 255, cin = (t >> 8) & 7, tap = t >> 11;
    W1p[t] = (cin < 5) ? (double)w1[oc * 125 + cin * 25 + tap] : 0.0;
}
__global__ void repack_w2(const float* __restrict__ w2, double* __restrict__ W2p) {
    int t = blockIdx.x * 256 + threadIdx.x;           // [(tap*256+cin)*256+oc]
    if (t >= 9 * 256 * 256) return;
    int oc = t & 255, cin = (t >> 8) & 255, tap = t >> 16;
    W2p[t] = (double)w2[((oc << 8) | cin) * 9 + tap];
}
__global__ void repack_w3(const float* __restrict__ w3, double* __restrict__ W3p) {
    int t = blockIdx.x * 256 + threadIdx.x;           // [cin*256+oc]
    if (t >= 256 * 256) return;
    int oc = t & 255, cin = t >> 8;
    W3p[t] = (double)w3[oc * 256 + cin];
}

// ------------------------------- launcher ----------------------------------
extern "C" void kernel_launch(void* const* d_in, const int* in_sizes, int n_in,
                              void* d_out, int out_size, void* d_ws, size_t ws_size,
                              hipStream_t stream)
{
    const float* x  = (const float*)d_in[0];
    const float* w1 = (const float*)d_in[1];
    const float* b1 = (const float*)d_in[2];
    const float* w2 = (const float*)d_in[3];
    const float* b2 = (const float*)d_in[4];
    const float* w3 = (const float*)d_in[5];
    const float* b3 = (const float*)d_in[6];
    const float* w4 = (const float*)d_in[7];
    const float* b4 = (const float*)d_in[8];
    float* out = (float*)d_out;                      // f32 output

    char* ws = (char*)d_ws;
    double* W1p  = (double*)(ws);                    //   409,600 B
    double* W2p  = (double*)(ws + 409600ull);        // 4,718,592 B
    double* W3p  = (double*)(ws + 5128192ull);       //   524,288 B
    double* h0   = (double*)(ws + 5652480ull);       // 4,194,304 B
    double* xp64 = (double*)(ws + 9846784ull);       // 2,097,152 B
    char*  bufs  = ws + 11943936ull;
    const size_t base_need = 11943936ull;
    const size_t ROWB = 524288ull;                   // 256*256 f64 per row

    int R = 2;                                       // tier visible via grids
    {
        const int cand[5] = {32, 16, 8, 4, 2};
        for (int ci = 0; ci < 5; ++ci) {
            int r = cand[ci];
            size_t need = base_need + (size_t)(2 * r + 6) * ROWB;
            if (ws_size >= need) { R = r; break; }
        }
    }
    double* h1 = (double*)bufs;                      // (R+4) rows
    double* h2 = (double*)(bufs + (size_t)(R + 4) * ROWB); // (R+2) rows
    double* h3 = h1;                                 // alias (h1 dead post-conv2)

    repack_w1<<<200, 256, 0, stream>>>(w1, W1p);
    repack_w2<<<2304, 256, 0, stream>>>(w2, W2p);
    repack_w3<<<256, 256, 0, stream>>>(w3, W3p);
    xinit_kernel<<<NPIX / 256, 256, 0, stream>>>(x, xp64);

    for (int it = 0; it < 5; ++it) {                 // n_it = 5 (setup constant)
        for (int b = 0; b < 4; ++b) {
            const int pbase = b << 16;
            stencil_kernel<<<256, 256, 0, stream>>>(x, xp64, h0, pbase);
            for (int r0 = 0; r0 < 256; r0 += R) {
                // h1 rows = global [r0-2, r0+R+2)
                conv_gemm<8, 5, 5, 8, true><<<dim3((R + 4) * 4, 2), 256, 0, stream>>>(
                    h0, W1p, b1, h1, r0 - 2, 0);
                // h2 rows = global [r0-1, r0+R+1); src h1 base r0-2 -> delta 1
                conv_gemm<256, 3, 3, 16, false><<<dim3((R + 2) * 4, 2), 256, 0, stream>>>(
                    h1, W2p, b2, h2, 0, 1);
                // h3 rows same as h2; delta 0
                conv_gemm<256, 1, 1, 16, false><<<dim3((R + 2) * 4, 2), 256, 0, stream>>>(
                    h2, W3p, b3, h3, 0, 0);
                // out rows [r0, r0+R); src h3 base r0-1 -> delta 1
                conv4_sig<<<R * 4, 256, 0, stream>>>(h3, w4, b4, out, xp64, pbase, r0, 1);
            }
        }
    }
}

// Round 6
// 84075.269 us; speedup vs baseline: 1.7366x; 1.7366x over previous
//
#include <hip/hip_runtime.h>
#include <hip/hip_bf16.h>

// ---------------------------------------------------------------------------
// FULL FLOAT64 pipeline (round-4 established: state must be f64-faithful —
// fp32-level noise on xp flips ~12 borderline binarizations/iter -> fail).
// Round-6: round-5 perf fixes kept; the round-5 strip-boundary RACE is fixed
// by double-buffering xp (stencil reads xp_old, conv4 writes xp_new, swap
// per iteration). Round-5 read halo rows of xp64 already overwritten by the
// previous strip's conv4 in the SAME iteration -> 0.08 boundary errors.
//
// B=4, H=W=256; batches independent; strips of R rows, halo recompute.
//   h0 strip: [nimg][(R+8) rows][256][8]  f64  (conv1 needs +-2 of h1 rows)
//   h1 strip: [nimg][(R+4)][256][256] f64 ; h2: [nimg][(R+2)][256][256]
//   h3 = h1 alias (h1 dead after conv2); same per-image stride as h1
//   packed weights f64: Wp[k*256+oc], k = tap*CIN+cin (tap-major)
//   xpA/xpB: [NPIX] f64 ping-pong state; d_out: [NPIX] f32 (written per iter)
// ---------------------------------------------------------------------------

#define NPIX (4 * 256 * 256)

// ---------------------- x (f32) -> xp (f64) init ---------------------------
__global__ __launch_bounds__(256) void xinit_kernel(
    const float* __restrict__ x, double* __restrict__ xp64)
{
    int p = blockIdx.x * 256 + threadIdx.x;
    xp64[p] = (double)x[p];
}

// ------------------- stencil features, strip-wise, per image ---------------
// grid (R+8, nimg); block row = strip-local row; global row wraps.
// Reads xp_old ONLY (never the buffer conv4 writes this iteration).
__global__ __launch_bounds__(256) void stencil_strip(
    const float* __restrict__ x, const double* __restrict__ xp,
    double* __restrict__ h0, size_t h0_is,
    int gbase, int r0m4)
{
    int img = blockIdx.y;
    int pbase = (gbase + img) << 16;
    int y = (r0m4 + blockIdx.x) & 255;
    int col = threadIdx.x;
    double q[8];
    int s = 0, idx = 0;
    #pragma unroll
    for (int i = -1; i <= 1; ++i)
        #pragma unroll
        for (int j = -1; j <= 1; ++j) {
            if (i == 0 && j == 0) continue;
            int ys = (y - i) & 255, xs = (col - j) & 255;
            double v = xp[pbase + ((ys << 8) | xs)];
            q[idx++] = v;
            s += (v > 0.5) ? 1 : 0;
        }
    double c = xp[pbase + ((y << 8) | col)];
    bool alive = c > 0.5;
    bool binnext = (s == 3) || (alive && s == 2);
    double c0 = 1.0, c1 = 0.0, c2 = 0.0, c3 = 0.0;   // count DP, ref order
    #pragma unroll
    for (int k = 0; k < 8; ++k) {
        double qq = q[k], r = 1.0 - qq;
        c3 = c3 * r + c2 * qq;
        c2 = c2 * r + c1 * qq;
        c1 = c1 * r + c0 * qq;
        c0 = c0 * r;
    }
    double xpred = c3 + c2 * c;
    double* o = h0 + img * h0_is +
                ((size_t)blockIdx.x * 256 + col) * 8;
    o[0] = (double)x[pbase + ((y << 8) | col)];
    o[1] = c;
    o[2] = alive ? 1.0 : 0.0;
    o[3] = xpred;
    o[4] = binnext ? 1.0 : 0.0;
    o[5] = 0.0; o[6] = 0.0; o[7] = 0.0;
}

// ------------------- f64 direct-conv GEMM (Cout=256) -----------------------
// Block tile: 128 px x 128 oc, 256 threads, 8x8/thread.
//   thread px  = pm0 + tm*8 + i   (tm = tid>>4, i 0..7)
//   thread oc  = on0 + tn + 16*j  (tn = tid&15, j 0..7)  <- conflict-free bv
// src row = yl + dy + delta (strip-local, halo pre-sized; col wraps &255).
template<int CIN, int TK, int KH, int KW>
__global__ __launch_bounds__(256, 2) void conv_gemm(
    const double* __restrict__ A,    // [aRows, 256, CIN] per image
    size_t a_is,                     // per-image A stride (elements)
    const double* __restrict__ Wp,   // [KH*KW*CIN, 256]
    const float* __restrict__ bias,  // [256] f32
    double* __restrict__ O,          // [oRows, 256, 256] per image
    size_t o_is,
    int delta)
{
    constexpr int PW = KW / 2, PH = KH / 2;
    constexpr int CHUNKS = CIN / TK;
    __shared__ double Asmem[TK][130];   // [k][px] transposed
    __shared__ double Wsmem[TK][128];   // [k][oc]

    const double* Ai = A + blockIdx.z * a_is;
    double* Oi = O + blockIdx.z * o_is;

    const int tid = threadIdx.x;
    const int pm0 = blockIdx.x * 128;
    const int on0 = blockIdx.y * 128;
    const int tn = tid & 15, tm = tid >> 4;

    // A staging: LPP lanes per pixel (double2 each)
    constexpr int LPP = TK / 2;
    constexpr int PPR = 256 / LPP;
    constexpr int ROUNDS = 128 / PPR;
    const int part = tid % LPP;
    const int pixA = tid / LPP;
    // W staging: 4 rows per pass (256 threads x double2)
    const int wrow = tid >> 6;
    const int wcol = (tid & 63) << 1;

    double acc[8][8] = {};

    for (int tap = 0; tap < KH * KW; ++tap) {
        const int dy = tap / KW - PH, dx = tap % KW - PW;
        for (int cc = 0; cc < CHUNKS; ++cc) {
            const int c0 = cc * TK;
            const int kglob = tap * CIN + c0;
            #pragma unroll
            for (int r = 0; r < TK / 4; ++r) {
                int row = r * 4 + wrow;
                *(double2*)&Wsmem[row][wcol] =
                    *(const double2*)&Wp[(size_t)(kglob + row) * 256 + on0 + wcol];
            }
            #pragma unroll
            for (int r = 0; r < ROUNDS; ++r) {
                int pix = r * PPR + pixA;
                int pl = pm0 + pix;
                int yl = pl >> 8, col = pl & 255;
                int xs = (col + dx) & 255;
                int srcpx = ((yl + dy + delta) << 8) | xs;
                const double2 v = *(const double2*)(
                    Ai + (size_t)srcpx * CIN + c0 + part * 2);
                Asmem[part * 2 + 0][pix] = v.x;
                Asmem[part * 2 + 1][pix] = v.y;
            }
            __syncthreads();
            #pragma unroll
            for (int k = 0; k < TK; ++k) {
                double av[8], bv[8];
                #pragma unroll
                for (int i = 0; i < 8; ++i) av[i] = Asmem[k][tm * 8 + i];
                #pragma unroll
                for (int j = 0; j < 8; ++j) bv[j] = Wsmem[k][tn + 16 * j];
                #pragma unroll
                for (int i = 0; i < 8; ++i)
                    #pragma unroll
                    for (int j = 0; j < 8; ++j)
                        acc[i][j] = fma(av[i], bv[j], acc[i][j]);
            }
            __syncthreads();
        }
    }

    double bb[8];
    #pragma unroll
    for (int j = 0; j < 8; ++j) bb[j] = (double)bias[on0 + tn + 16 * j];
    #pragma unroll
    for (int i = 0; i < 8; ++i) {
        int pl = pm0 + tm * 8 + i;
        double* dst = Oi + (size_t)pl * 256 + on0;
        #pragma unroll
        for (int j = 0; j < 8; ++j)
            dst[tn + 16 * j] = fmax(acc[i][j] + bb[j], 0.0);
    }
}

// --------------- conv4: 256->1, 3x3, + sigmoid, wave-per-pixel -------------
// grid (R*4, nimg). Reads h3 strip (delta=1); writes out f32 + xp_new f64.
__global__ __launch_bounds__(256) void conv4_sig(
    const double* __restrict__ H3, size_t h3_is,
    const float* __restrict__ w4, const float* __restrict__ b4,
    float* __restrict__ out, double* __restrict__ xp_new,
    int gbase, int r0)
{
    __shared__ double w4s[2304];     // w4[cin][kh][kw] f64
    int tid = threadIdx.x;
    for (int i = tid; i < 2304; i += 256) w4s[i] = (double)w4[i];
    __syncthreads();
    const double* H3i = H3 + blockIdx.y * h3_is;
    int pbase = (gbase + blockIdx.y) << 16;
    int lane = tid & 63, wv = tid >> 6;
    int p0 = blockIdx.x * 64 + wv * 16;
    for (int pi = 0; pi < 16; ++pi) {
        int pl = p0 + pi;
        int yl = pl >> 8, col = pl & 255;
        double acc = 0.0;
        #pragma unroll
        for (int tap = 0; tap < 9; ++tap) {
            int row = yl + tap / 3 - 1 + 1;                 // delta = 1
            int xs = (col + tap % 3 - 1) & 255;
            const double* src = H3i + (size_t)((row << 8) | xs) * 256;
            #pragma unroll
            for (int j = 0; j < 4; ++j) {
                int c = lane + 64 * j;
                acc = fma(src[c], w4s[c * 9 + tap], acc);
            }
        }
        #pragma unroll
        for (int off = 32; off; off >>= 1) acc += __shfl_xor(acc, off, 64);
        if (lane == 0) {
            double v = acc + (double)b4[0];
            double s = 1.0 / (1.0 + exp(-v));
            int p = pbase + (((r0 + yl) << 8) | col);
            out[p] = (float)s;
            xp_new[p] = s;
        }
    }
}

// ----------------------------- weight repacks (f32 -> f64) -----------------
__global__ void repack_w1(const float* __restrict__ w1, double* __restrict__ W1p) {
    int t = blockIdx.x * 256 + threadIdx.x;           // [(tap*8+cin)*256+oc]
    if (t >= 25 * 8 * 256) return;
    int oc = t & 255, cin = (t >> 8) & 7, tap = t >> 11;
    W1p[t] = (cin < 5) ? (double)w1[oc * 125 + cin * 25 + tap] : 0.0;
}
__global__ void repack_w2(const float* __restrict__ w2, double* __restrict__ W2p) {
    int t = blockIdx.x * 256 + threadIdx.x;           // [(tap*256+cin)*256+oc]
    if (t >= 9 * 256 * 256) return;
    int oc = t & 255, cin = (t >> 8) & 255, tap = t >> 16;
    W2p[t] = (double)w2[((oc << 8) | cin) * 9 + tap];
}
__global__ void repack_w3(const float* __restrict__ w3, double* __restrict__ W3p) {
    int t = blockIdx.x * 256 + threadIdx.x;           // [cin*256+oc]
    if (t >= 256 * 256) return;
    int oc = t & 255, cin = t >> 8;
    W3p[t] = (double)w3[oc * 256 + cin];
}

// ------------------------------- launcher ----------------------------------
extern "C" void kernel_launch(void* const* d_in, const int* in_sizes, int n_in,
                              void* d_out, int out_size, void* d_ws, size_t ws_size,
                              hipStream_t stream)
{
    const float* x  = (const float*)d_in[0];
    const float* w1 = (const float*)d_in[1];
    const float* b1 = (const float*)d_in[2];
    const float* w2 = (const float*)d_in[3];
    const float* b2 = (const float*)d_in[4];
    const float* w3 = (const float*)d_in[5];
    const float* b3 = (const float*)d_in[6];
    const float* w4 = (const float*)d_in[7];
    const float* b4 = (const float*)d_in[8];
    float* out = (float*)d_out;                      // f32 output

    char* ws = (char*)d_ws;
    double* W1p = (double*)(ws);                     //   409,600 B
    double* W2p = (double*)(ws + 409600ull);         // 4,718,592 B
    double* W3p = (double*)(ws + 5128192ull);        //   524,288 B
    double* xpA = (double*)(ws + 5652480ull);        // 2,097,152 B
    double* xpB = (double*)(ws + 7749632ull);        // 2,097,152 B
    char*  bufs = ws + 9846784ull;
    const size_t base_need = 9846784ull;
    const size_t ROWD  = 524288ull;                  // 256*256 f64 row bytes
    const size_t ROWH0 = 16384ull;                   // 256*8 f64 row bytes

    // (nimg, R) tier ladder — largest-need first; floor fits ws >= ~15 MB
    const int cand_n[10] = {4, 4, 2, 2, 1, 2, 1, 1, 1, 1};
    const int cand_r[10] = {32, 16, 32, 16, 32, 8, 16, 8, 4, 2};
    int NIMG = 1, R = 2;
    for (int ci = 0; ci < 10; ++ci) {
        int n = cand_n[ci], r = cand_r[ci];
        size_t need = base_need + (size_t)n *
            ((size_t)(r + 8) * ROWH0 + (size_t)(r + 4) * ROWD + (size_t)(r + 2) * ROWD);
        if (ws_size >= need) { NIMG = n; R = r; break; }
    }
    double* h0 = (double*)bufs;
    double* h1 = (double*)(bufs + (size_t)NIMG * (R + 8) * ROWH0);
    double* h2 = (double*)((char*)h1 + (size_t)NIMG * (R + 4) * ROWD);
    double* h3 = h1;                                 // alias, same stride as h1
    const size_t h0_is = (size_t)(R + 8) * 256 * 8;  // element strides
    const size_t h1_is = (size_t)(R + 4) * 256 * 256;
    const size_t h2_is = (size_t)(R + 2) * 256 * 256;

    repack_w1<<<200, 256, 0, stream>>>(w1, W1p);
    repack_w2<<<2304, 256, 0, stream>>>(w2, W2p);
    repack_w3<<<256, 256, 0, stream>>>(w3, W3p);
    xinit_kernel<<<NPIX / 256, 256, 0, stream>>>(x, xpA);

    for (int it = 0; it < 5; ++it) {                 // n_it = 5 (setup constant)
        const double* xp_rd = (it & 1) ? xpB : xpA;  // ping-pong: no intra-iter
        double*       xp_wr = (it & 1) ? xpA : xpB;  // read-after-write hazard
        for (int g = 0; g < 4; g += NIMG) {
            for (int r0 = 0; r0 < 256; r0 += R) {
                // h0 rows = global [r0-4, r0+R+4)
                stencil_strip<<<dim3(R + 8, NIMG), 256, 0, stream>>>(
                    x, xp_rd, h0, h0_is, g, r0 - 4);
                // h1 rows = global [r0-2, r0+R+2); src h0 base r0-4 -> delta 2
                conv_gemm<8, 8, 5, 5><<<dim3((R + 4) * 2, 2, NIMG), 256, 0, stream>>>(
                    h0, h0_is, W1p, b1, h1, h1_is, 2);
                // h2 rows = global [r0-1, r0+R+1); src h1 base r0-2 -> delta 1
                conv_gemm<256, 16, 3, 3><<<dim3((R + 2) * 2, 2, NIMG), 256, 0, stream>>>(
                    h1, h1_is, W2p, b2, h2, h2_is, 1);
                // h3 rows same as h2; delta 0 (h3 aliases h1's buffer/stride)
                conv_gemm<256, 16, 1, 1><<<dim3((R + 2) * 2, 2, NIMG), 256, 0, stream>>>(
                    h2, h2_is, W3p, b3, h3, h1_is, 0);
                // out rows [r0, r0+R); src h3 base r0-1 -> delta 1
                conv4_sig<<<dim3(R * 4, NIMG), 256, 0, stream>>>(
                    h3, h1_is, w4, b4, out, xp_wr, g, r0);
            }
        }
    }
}

// Round 7
// 70961.365 us; speedup vs baseline: 2.0575x; 1.1848x over previous
//
#include <hip/hip_runtime.h>
#include <hip/hip_bf16.h>

// ---------------------------------------------------------------------------
// FULL FLOAT64 pipeline (rounds 4/5: state + activations must be f64 —
// fp32-level noise flips borderline binarizations -> 0.05-scale errors).
// Round-7: round-6 counters showed grid starvation (Occupancy 12.5%,
// VALUBusy 26%, per-active-CU ~100%). Fix: batch G (image,strip) JOBS into
// grid.z per launch with per-slot buffers; (R,G) tier ladder maximizes
// blocks-per-launch under ws_size. Plus register prefetch of next chunk's
// global loads (1 wave/SIMD cannot hide global latency otherwise).
// Summation order (tap -> cc -> k) unchanged -> bit-identical numerics.
//
//   job j = img * NSTRIP + s ; img = j >> ns_shift ; r0 = (j & (NSTRIP-1))*R
//   h0 slot: [(R+8) rows][256][8] f64 ; h1: [(R+4)][256][256] ;
//   h2: [(R+2)][256][256] ; h3 = h1 alias
//   packed weights f64: Wp[k*256+oc], k = tap*CIN+cin (tap-major)
//   xpA/xpB: [NPIX] f64 ping-pong state; d_out: [NPIX] f32
// ---------------------------------------------------------------------------

#define NPIX (4 * 256 * 256)

// ---------------------- x (f32) -> xp (f64) init ---------------------------
__global__ __launch_bounds__(256) void xinit_kernel(
    const float* __restrict__ x, double* __restrict__ xp64)
{
    int p = blockIdx.x * 256 + threadIdx.x;
    xp64[p] = (double)x[p];
}

// ------------------- stencil features, job-sliced --------------------------
// grid (R+8, G); blockIdx.y = slot; job = job0 + slot.
__global__ __launch_bounds__(256) void stencil_strip(
    const float* __restrict__ x, const double* __restrict__ xp,
    double* __restrict__ h0, size_t h0_is,
    int job0, int ns_shift, int R)
{
    int slot = blockIdx.y;
    int j = job0 + slot;
    int img = j >> ns_shift;
    int r0 = (j & ((1 << ns_shift) - 1)) * R;
    int pbase = img << 16;
    int y = (r0 - 4 + blockIdx.x) & 255;
    int col = threadIdx.x;
    double q[8];
    int s = 0, idx = 0;
    #pragma unroll
    for (int i = -1; i <= 1; ++i)
        #pragma unroll
        for (int jj = -1; jj <= 1; ++jj) {
            if (i == 0 && jj == 0) continue;
            int ys = (y - i) & 255, xs = (col - jj) & 255;
            double v = xp[pbase + ((ys << 8) | xs)];
            q[idx++] = v;
            s += (v > 0.5) ? 1 : 0;
        }
    double c = xp[pbase + ((y << 8) | col)];
    bool alive = c > 0.5;
    bool binnext = (s == 3) || (alive && s == 2);
    double c0 = 1.0, c1 = 0.0, c2 = 0.0, c3 = 0.0;   // count DP, ref order
    #pragma unroll
    for (int k = 0; k < 8; ++k) {
        double qq = q[k], r = 1.0 - qq;
        c3 = c3 * r + c2 * qq;
        c2 = c2 * r + c1 * qq;
        c1 = c1 * r + c0 * qq;
        c0 = c0 * r;
    }
    double xpred = c3 + c2 * c;
    double* o = h0 + slot * h0_is + ((size_t)blockIdx.x * 256 + col) * 8;
    o[0] = (double)x[pbase + ((y << 8) | col)];
    o[1] = c;
    o[2] = alive ? 1.0 : 0.0;
    o[3] = xpred;
    o[4] = binnext ? 1.0 : 0.0;
    o[5] = 0.0; o[6] = 0.0; o[7] = 0.0;
}

// ------------------- f64 direct-conv GEMM (Cout=256) -----------------------
// Block tile: 128 px x 128 oc, 256 threads, 8x8/thread.
//   thread px = pm0 + tm*8 + i ; thread oc = on0 + tn + 16*j (conflict-free)
// grid.z = slot. Register prefetch of next chunk's global loads.
template<int CIN, int TK, int KH, int KW>
__global__ __launch_bounds__(256, 2) void conv_gemm(
    const double* __restrict__ A,    // [aRows, 256, CIN] per slot
    size_t a_is,
    const double* __restrict__ Wp,   // [KH*KW*CIN, 256]
    const float* __restrict__ bias,  // [256] f32
    double* __restrict__ O,          // [oRows, 256, 256] per slot
    size_t o_is,
    int delta)
{
    constexpr int PW = KW / 2, PH = KH / 2;
    constexpr int CHUNKS = CIN / TK;          // power of two (1 or 16)
    constexpr int NCH = KH * KW * CHUNKS;
    constexpr int WR = TK / 4;                // W double2 loads per thread
    constexpr int LPP = TK / 2;               // lanes per pixel (A staging)
    constexpr int PPR = 256 / LPP;
    constexpr int ROUNDS = 128 / PPR;

    __shared__ double Asmem[TK][130];         // [k][px] transposed
    __shared__ double Wsmem[TK][128];         // [k][oc]

    const double* Ai = A + blockIdx.z * a_is;
    double* Oi = O + blockIdx.z * o_is;

    const int tid = threadIdx.x;
    const int pm0 = blockIdx.x * 128;
    const int on0 = blockIdx.y * 128;
    const int tn = tid & 15, tm = tid >> 4;
    const int part = tid % LPP;
    const int pixA = tid / LPP;
    const int wrow = tid >> 6;
    const int wcol = (tid & 63) << 1;

    double2 wreg[WR], areg[ROUNDS];

    auto prefetch = [&](int ch) {
        int tap = ch / CHUNKS;                // CHUNKS pow2 -> shift
        int cc = ch & (CHUNKS - 1);
        int dy = tap / KW - PH, dx = tap % KW - PW;
        int c0 = cc * TK;
        int kglob = tap * CIN + c0;
        #pragma unroll
        for (int r = 0; r < WR; ++r) {
            int row = r * 4 + wrow;
            wreg[r] = *(const double2*)&Wp[(size_t)(kglob + row) * 256 + on0 + wcol];
        }
        #pragma unroll
        for (int r = 0; r < ROUNDS; ++r) {
            int pix = r * PPR + pixA;
            int pl = pm0 + pix;
            int yl = pl >> 8, col = pl & 255;
            int xs = (col + dx) & 255;
            int srcpx = ((yl + dy + delta) << 8) | xs;
            areg[r] = *(const double2*)(Ai + (size_t)srcpx * CIN + c0 + part * 2);
        }
    };

    double acc[8][8] = {};
    prefetch(0);
    #pragma unroll 1
    for (int ch = 0; ch < NCH; ++ch) {
        __syncthreads();                      // prev chunk's readers done
        #pragma unroll
        for (int r = 0; r < WR; ++r)
            *(double2*)&Wsmem[r * 4 + wrow][wcol] = wreg[r];
        #pragma unroll
        for (int r = 0; r < ROUNDS; ++r) {
            int pix = r * PPR + pixA;
            Asmem[part * 2 + 0][pix] = areg[r].x;
            Asmem[part * 2 + 1][pix] = areg[r].y;
        }
        __syncthreads();
        if (ch + 1 < NCH) prefetch(ch + 1);   // in flight during compute
        #pragma unroll
        for (int k = 0; k < TK; ++k) {
            double av[8], bv[8];
            #pragma unroll
            for (int i = 0; i < 8; ++i) av[i] = Asmem[k][tm * 8 + i];
            #pragma unroll
            for (int j = 0; j < 8; ++j) bv[j] = Wsmem[k][tn + 16 * j];
            #pragma unroll
            for (int i = 0; i < 8; ++i)
                #pragma unroll
                for (int j = 0; j < 8; ++j)
                    acc[i][j] = fma(av[i], bv[j], acc[i][j]);
        }
    }

    double bb[8];
    #pragma unroll
    for (int j = 0; j < 8; ++j) bb[j] = (double)bias[on0 + tn + 16 * j];
    #pragma unroll
    for (int i = 0; i < 8; ++i) {
        int pl = pm0 + tm * 8 + i;
        double* dst = Oi + (size_t)pl * 256 + on0;
        #pragma unroll
        for (int j = 0; j < 8; ++j)
            dst[tn + 16 * j] = fmax(acc[i][j] + bb[j], 0.0);
    }
}

// --------------- conv4: 256->1, 3x3, + sigmoid, wave-per-pixel -------------
// grid (R*4, G); blockIdx.y = slot; job = job0 + slot.
__global__ __launch_bounds__(256) void conv4_sig(
    const double* __restrict__ H3, size_t h3_is,
    const float* __restrict__ w4, const float* __restrict__ b4,
    float* __restrict__ out, double* __restrict__ xp_new,
    int job0, int ns_shift, int R)
{
    __shared__ double w4s[2304];     // w4[cin][kh][kw] f64
    int tid = threadIdx.x;
    for (int i = tid; i < 2304; i += 256) w4s[i] = (double)w4[i];
    __syncthreads();
    int slot = blockIdx.y;
    int j = job0 + slot;
    int img = j >> ns_shift;
    int r0 = (j & ((1 << ns_shift) - 1)) * R;
    const double* H3i = H3 + slot * h3_is;
    int pbase = img << 16;
    int lane = tid & 63, wv = tid >> 6;
    int p0 = blockIdx.x * 64 + wv * 16;
    for (int pi = 0; pi < 16; ++pi) {
        int pl = p0 + pi;
        int yl = pl >> 8, col = pl & 255;
        double acc = 0.0;
        #pragma unroll
        for (int tap = 0; tap < 9; ++tap) {
            int row = yl + tap / 3 - 1 + 1;                 // delta = 1
            int xs = (col + tap % 3 - 1) & 255;
            const double* src = H3i + (size_t)((row << 8) | xs) * 256;
            #pragma unroll
            for (int jj = 0; jj < 4; ++jj) {
                int c = lane + 64 * jj;
                acc = fma(src[c], w4s[c * 9 + tap], acc);
            }
        }
        #pragma unroll
        for (int off = 32; off; off >>= 1) acc += __shfl_xor(acc, off, 64);
        if (lane == 0) {
            double v = acc + (double)b4[0];
            double s = 1.0 / (1.0 + exp(-v));
            int p = pbase + (((r0 + yl) << 8) | col);
            out[p] = (float)s;
            xp_new[p] = s;
        }
    }
}

// ----------------------------- weight repacks (f32 -> f64) -----------------
__global__ void repack_w1(const float* __restrict__ w1, double* __restrict__ W1p) {
    int t = blockIdx.x * 256 + threadIdx.x;           // [(tap*8+cin)*256+oc]
    if (t >= 25 * 8 * 256) return;
    int oc = t & 255, cin = (t >> 8) & 7, tap = t >> 11;
    W1p[t] = (cin < 5) ? (double)w1[oc * 125 + cin * 25 + tap] : 0.0;
}
__global__ void repack_w2(const float* __restrict__ w2, double* __restrict__ W2p) {
    int t = blockIdx.x * 256 + threadIdx.x;           // [(tap*256+cin)*256+oc]
    if (t >= 9 * 256 * 256) return;
    int oc = t & 255, cin = (t >> 8) & 255, tap = t >> 16;
    W2p[t] = (double)w2[((oc << 8) | cin) * 9 + tap];
}
__global__ void repack_w3(const float* __restrict__ w3, double* __restrict__ W3p) {
    int t = blockIdx.x * 256 + threadIdx.x;           // [cin*256+oc]
    if (t >= 256 * 256) return;
    int oc = t & 255, cin = t >> 8;
    W3p[t] = (double)w3[oc * 256 + cin];
}

// ------------------------------- launcher ----------------------------------
extern "C" void kernel_launch(void* const* d_in, const int* in_sizes, int n_in,
                              void* d_out, int out_size, void* d_ws, size_t ws_size,
                              hipStream_t stream)
{
    const float* x  = (const float*)d_in[0];
    const float* w1 = (const float*)d_in[1];
    const float* b1 = (const float*)d_in[2];
    const float* w2 = (const float*)d_in[3];
    const float* b2 = (const float*)d_in[4];
    const float* w3 = (const float*)d_in[5];
    const float* b3 = (const float*)d_in[6];
    const float* w4 = (const float*)d_in[7];
    const float* b4 = (const float*)d_in[8];
    float* out = (float*)d_out;                      // f32 output

    char* ws = (char*)d_ws;
    double* W1p = (double*)(ws);                     //   409,600 B
    double* W2p = (double*)(ws + 409600ull);         // 4,718,592 B
    double* W3p = (double*)(ws + 5128192ull);        //   524,288 B
    double* xpA = (double*)(ws + 5652480ull);        // 2,097,152 B
    double* xpB = (double*)(ws + 7749632ull);        // 2,097,152 B
    char*  bufs = ws + 9846784ull;
    const size_t base_need = 9846784ull;
    const size_t ROWD  = 524288ull;                  // 256*256 f64 row bytes
    const size_t ROWH0 = 16384ull;                   // 256*8 f64 row bytes

    // (R, G) tier ladder: maximize per-launch blocks under ws_size.
    // conv2 grid = ((R+2)*2, 2, G) -> G*(R+2)*4 blocks (tier visible there).
    const int cand_r[15] = {32, 32, 16, 32, 16, 8, 16, 8, 4, 8, 16, 4, 8, 4, 2};
    const int cand_g[15] = { 4,  3,  4,  2,  3, 4,  2, 3, 4, 2,  1, 2, 1, 1, 1};
    int R = 2, G = 1;
    for (int ci = 0; ci < 15; ++ci) {
        int r = cand_r[ci], g = cand_g[ci];
        size_t need = base_need + (size_t)g *
            ((size_t)(r + 8) * ROWH0 + (size_t)(2 * r + 6) * ROWD);
        if (ws_size >= need) { R = r; G = g; break; }
    }
    int ns_shift = (R == 32) ? 3 : (R == 16) ? 4 : (R == 8) ? 5 : (R == 4) ? 6 : 7;
    const int NSTRIP = 256 / R;
    const int jobs = 4 * NSTRIP;

    double* h0 = (double*)bufs;
    double* h1 = (double*)(bufs + (size_t)G * (R + 8) * ROWH0);
    double* h2 = (double*)((char*)h1 + (size_t)G * (R + 4) * ROWD);
    double* h3 = h1;                                 // alias, stride h1_is
    const size_t h0_is = (size_t)(R + 8) * 256 * 8;  // element strides
    const size_t h1_is = (size_t)(R + 4) * 256 * 256;
    const size_t h2_is = (size_t)(R + 2) * 256 * 256;

    repack_w1<<<200, 256, 0, stream>>>(w1, W1p);
    repack_w2<<<2304, 256, 0, stream>>>(w2, W2p);
    repack_w3<<<256, 256, 0, stream>>>(w3, W3p);
    xinit_kernel<<<NPIX / 256, 256, 0, stream>>>(x, xpA);

    for (int it = 0; it < 5; ++it) {                 // n_it = 5 (setup constant)
        const double* xp_rd = (it & 1) ? xpB : xpA;  // ping-pong: no intra-iter
        double*       xp_wr = (it & 1) ? xpA : xpB;  // RAW hazard (round 5 bug)
        for (int j0 = 0; j0 < jobs; j0 += G) {
            int g = (jobs - j0 < G) ? (jobs - j0) : G;
            stencil_strip<<<dim3(R + 8, g), 256, 0, stream>>>(
                x, xp_rd, h0, h0_is, j0, ns_shift, R);
            conv_gemm<8, 8, 5, 5><<<dim3((R + 4) * 2, 2, g), 256, 0, stream>>>(
                h0, h0_is, W1p, b1, h1, h1_is, 2);
            conv_gemm<256, 16, 3, 3><<<dim3((R + 2) * 2, 2, g), 256, 0, stream>>>(
                h1, h1_is, W2p, b2, h2, h2_is, 1);
            conv_gemm<256, 16, 1, 1><<<dim3((R + 2) * 2, 2, g), 256, 0, stream>>>(
                h2, h2_is, W3p, b3, h3, h1_is, 0);
            conv4_sig<<<dim3(R * 4, g), 256, 0, stream>>>(
                h3, h1_is, w4, b4, out, xp_wr, j0, ns_shift, R);
        }
    }
}